// Round 18
// baseline (394.900 us; speedup 1.0000x reference)
//
#include <hip/hip_runtime.h>
#include <cstdint>
#include <math.h>

typedef float f32x4 __attribute__((ext_vector_type(4)));
typedef __bf16 bf16x8 __attribute__((ext_vector_type(8)));
typedef unsigned short us4 __attribute__((ext_vector_type(4)));
typedef unsigned short us8 __attribute__((ext_vector_type(8)));

#define DEV static __device__ __forceinline__

DEV unsigned short f2bf(float f){
  union { __bf16 h; unsigned short u; } cv; cv.h = (__bf16)f; return cv.u;
}
DEV float bf2f(unsigned short u){ return __uint_as_float((unsigned int)u << 16); }

DEV void gload16(const void* g, void* l){
  __builtin_amdgcn_global_load_lds((__attribute__((address_space(1))) void*)g,
                                   (__attribute__((address_space(3))) void*)l, 16, 0, 0);
}

// ---------------- fp32 -> bf16 weight conversion (streaming) ----------------
__global__ __launch_bounds__(256) void conv_kernel(const float* __restrict__ src,
    unsigned short* __restrict__ dst, int n8){
  int i = blockIdx.x*256 + threadIdx.x;
  if (i >= n8) return;
  float4 a = ((const float4*)src)[2*i];
  float4 b = ((const float4*)src)[2*i+1];
  us8 o = { f2bf(a.x), f2bf(a.y), f2bf(a.z), f2bf(a.w),
            f2bf(b.x), f2bf(b.y), f2bf(b.z), f2bf(b.w) };
  ((us8*)dst)[i] = o;
}

// ---------------- V transpose: vb[t][h*64+d] -> vt[h][d][t] ----------------
__global__ __launch_bounds__(256) void vtrans_kernel(const unsigned short* __restrict__ vb,
    unsigned short* __restrict__ vt){
  int tt = blockIdx.x, h = blockIdx.y;
  int t0 = tt*64;
  __shared__ unsigned short tile[64][72];
  int r = threadIdx.x >> 2, cb = (threadIdx.x & 3) * 16;
  const unsigned short* src = vb + (long long)(t0+r)*1024 + h*64 + cb;
  us8 a = *(const us8*)src;
  us8 b = *(const us8*)(src+8);
  #pragma unroll
  for (int i=0;i<8;++i){ tile[r][cb+i] = a[i]; tile[r][cb+8+i] = b[i]; }
  __syncthreads();
  unsigned short o[16];
  #pragma unroll
  for (int i=0;i<16;++i) o[i] = tile[cb+i][r];
  unsigned short* dst = vt + (long long)(h*64+r)*2048 + t0 + cb;
  *(us8*)dst = *(us8*)&o[0];
  *(us8*)(dst+8) = *(us8*)&o[8];
}

// ---------------- RMSNorm 1 ----------------
__global__ __launch_bounds__(256) void rmsnorm_kernel(const float* __restrict__ x, const float* __restrict__ w,
    unsigned short* __restrict__ ob){
  int t = blockIdx.x, tid = threadIdx.x;
  float4 xv = *(const float4*)(x + (long long)t*1024 + tid*4);
  float ss = xv.x*xv.x + xv.y*xv.y + xv.z*xv.z + xv.w*xv.w;
  for (int m=32;m;m>>=1) ss += __shfl_xor(ss,m);
  __shared__ float lds[4];
  if ((tid&63)==0) lds[tid>>6] = ss;
  __syncthreads();
  float tot = lds[0]+lds[1]+lds[2]+lds[3];
  float inv = rsqrtf(tot*(1.0f/1024.0f) + 1.1920928955078125e-07f);
  float4 wv = *(const float4*)(w + tid*4);
  us4 rb = { f2bf(xv.x*inv*wv.x), f2bf(xv.y*inv*wv.y), f2bf(xv.z*inv*wv.z), f2bf(xv.w*inv*wv.w) };
  *(us4*)&ob[(long long)t*1024 + tid*4] = rb;
}

// ---------------- RMSNorm 2 + fused router/top2 ----------------
__global__ __launch_bounds__(256) void rmsnorm2_kernel(const float* __restrict__ xp, int ksn, long long kstride,
    const float* __restrict__ w, const float* __restrict__ rw,
    float* __restrict__ x1, unsigned short* __restrict__ hb,
    float* __restrict__ probs, int* __restrict__ tope, float* __restrict__ topw, int* __restrict__ counts){
  int t = blockIdx.x, tid = threadIdx.x;
  long long b = (long long)t*1024 + tid*4;
  float4 xv = {0.f,0.f,0.f,0.f};
  for (int ks=0; ks<ksn; ++ks){
    float4 a = *(const float4*)(xp + ks*kstride + b);
    xv.x+=a.x; xv.y+=a.y; xv.z+=a.z; xv.w+=a.w;
  }
  *(float4*)(x1 + b) = xv;
  float ss = xv.x*xv.x + xv.y*xv.y + xv.z*xv.z + xv.w*xv.w;
  for (int m=32;m;m>>=1) ss += __shfl_xor(ss,m);
  __shared__ float lds[32];
  if ((tid&63)==0) lds[tid>>6] = ss;
  __syncthreads();
  float tot = lds[0]+lds[1]+lds[2]+lds[3];
  float inv = rsqrtf(tot*(1.0f/1024.0f) + 1.1920928955078125e-07f);
  float4 wv = *(const float4*)(w + tid*4);
  float r0 = xv.x*inv*wv.x, r1 = xv.y*inv*wv.y, r2 = xv.z*inv*wv.z, r3 = xv.w*inv*wv.w;
  us4 rb = { f2bf(r0), f2bf(r1), f2bf(r2), f2bf(r3) };
  *(us4*)&hb[b] = rb;
  float pe[8];
  #pragma unroll
  for (int e2=0;e2<8;++e2){
    float4 rv = *(const float4*)(rw + e2*1024 + tid*4);
    pe[e2] = r0*rv.x + r1*rv.y + r2*rv.z + r3*rv.w;
  }
  __syncthreads();
  #pragma unroll
  for (int e2=0;e2<8;++e2){
    float v = pe[e2];
    for (int m=32;m;m>>=1) v += __shfl_xor(v,m);
    if ((tid&63)==0) lds[(tid>>6)*8+e2] = v;
  }
  __syncthreads();
  if (tid==0){
    float lg[8], pp[8];
    #pragma unroll
    for (int e2=0;e2<8;++e2) lg[e2] = lds[e2]+lds[8+e2]+lds[16+e2]+lds[24+e2];
    float mx = lg[0];
    for (int e2=1;e2<8;++e2) mx = fmaxf(mx, lg[e2]);
    float s = 0.f;
    for (int e2=0;e2<8;++e2){ pp[e2] = __expf(lg[e2]-mx); s += pp[e2]; }
    float invs = 1.0f/s;
    int i0 = 0;
    for (int e2=1;e2<8;++e2) if (pp[e2] > pp[i0]) i0 = e2;
    int i1 = (i0==0)?1:0;
    for (int e2=0;e2<8;++e2) if (e2!=i0 && pp[e2] > pp[i1]) i1 = e2;
    for (int e2=0;e2<8;++e2) probs[t*8+e2] = pp[e2]*invs;
    float p0 = pp[i0], p1 = pp[i1], wsum = p0+p1;
    tope[t*2] = i0; tope[t*2+1] = i1;
    topw[t*2] = p0/wsum; topw[t*2+1] = p1/wsum;
    atomicAdd(&counts[i0],1); atomicAdd(&counts[i1],1);
  }
}

// ---------------- m97-replica GEMM  C[M,N] = A[M,K](bf16) * B[N,K]^T(bf16) ----------------
// BM=128, BN in {128,64}. 256 thr, 4 waves. BK=64, single-buffered LDS,
// global_load_lds both operands, pre-swizzled source c^(R&7); 2-barrier loop (m97/m114).
// EPI: 1 = fp32 (+resid if ks==0), 2 = gelu->bf16 rows rbase+lr, 3 = *wgt scatter fp32,
//      4 = plain bf16, 5 = *wgt scatter bf16, 6 = fused-RoPE qkv (q->Q2, k->K2, v->Cb)
template<int EPI, bool GATHER, int BN>
__global__ __launch_bounds__(256) void gemm_bb(
    const unsigned short* __restrict__ A, int lda,
    const unsigned short* __restrict__ Bb, long long bstride, int ldb,
    int M, int N, int K, int KS, long long ksoff,
    const int* __restrict__ counts, const int* __restrict__ offs,
    const int* __restrict__ tok_list, const float* __restrict__ wgt,
    const float* __restrict__ resid,
    float* __restrict__ Cf, unsigned short* __restrict__ Cb, int ldc,
    unsigned short* __restrict__ Q2, unsigned short* __restrict__ K2)
{
  constexpr int MF = (BN==128) ? 4 : 2;       // m-frags per wave
  constexpr int BLOADS = BN/32;               // B gload16 per thread
  const int z = blockIdx.z;
  const int e = z / KS, ks = z - e*KS;
  const int Me = counts ? counts[e] : M;
  const int by = blockIdx.y;
  if (by * 128 >= Me) return;
  const int rbase = offs ? offs[e] : 0;
  const int bx = blockIdx.x;
  const unsigned short* B = Bb + (long long)e * bstride;
  const int kn = K / KS;
  const int kbeg = ks * kn;

  __shared__ __align__(16) unsigned short As[128*64];
  __shared__ __align__(16) unsigned short Bs[BN*64];

  const int tid = threadIdx.x, lane = tid & 63, w = tid >> 6;
  const int wr = (BN==128) ? (w >> 1) : w;
  const int wc = (BN==128) ? (w & 1) : 0;
  const int l15 = lane & 15, l4 = lane >> 4;

  const unsigned short* asrc[4];
  #pragma unroll
  for (int j=0;j<4;++j){
    int G = j*256 + tid;
    int R = G >> 3, c = G & 7;
    int sc = c ^ (R & 7);
    int lr = by*128 + R; if (lr >= Me) lr = Me-1;
    int li = rbase + lr;
    int ar = GATHER ? (tok_list[li] >> 1) : li;
    asrc[j] = A + (long long)ar*lda + kbeg + sc*8;
  }
  const unsigned short* bsrc[BLOADS];
  #pragma unroll
  for (int j=0;j<BLOADS;++j){
    int G = j*256 + tid;
    int R = G >> 3, c = G & 7;
    int sc = c ^ (R & 7);
    bsrc[j] = B + (long long)(bx*BN + R)*ldb + kbeg + sc*8;
  }

  f32x4 acc[MF][4] = {};

  for (int k0 = 0; k0 < kn; k0 += 64){
    __syncthreads();
    #pragma unroll
    for (int j=0;j<4;++j) gload16(asrc[j] + k0, &As[(j*256+tid)*8]);
    #pragma unroll
    for (int j=0;j<BLOADS;++j) gload16(bsrc[j] + k0, &Bs[(j*256+tid)*8]);
    __syncthreads();
    #pragma unroll
    for (int kk=0;kk<2;++kk){
      bf16x8 af[MF], bfr[4];
      #pragma unroll
      for (int m=0;m<MF;++m){
        int R = wr*(MF*16) + m*16 + l15;
        int c = (l4 + 4*kk) ^ (R&7);
        af[m] = *(const bf16x8*)&As[R*64 + c*8];
      }
      #pragma unroll
      for (int n=0;n<4;++n){
        int R = wc*64 + n*16 + l15;
        int c = (l4 + 4*kk) ^ (R&7);
        bfr[n] = *(const bf16x8*)&Bs[R*64 + c*8];
      }
      #pragma unroll
      for (int m=0;m<MF;++m)
        #pragma unroll
        for (int n=0;n<4;++n)
          acc[m][n] = __builtin_amdgcn_mfma_f32_16x16x32_bf16(af[m], bfr[n], acc[m][n], 0, 0, 0);
    }
  }

  if constexpr (EPI == 6){
    // qkv with fused RoPE. N=3072: bx 0-15 = q heads, 16-31 = k heads, 32-47 = v.
    #pragma unroll
    for (int m=0;m<MF;++m){
      #pragma unroll
      for (int r2=0;r2<4;++r2){
        int lr = by*128 + wr*(MF*16) + m*16 + 4*l4 + r2;
        if (bx < 32){
          unsigned short* dst = (bx < 16) ? Q2 : K2;
          int h = bx & 15;
          #pragma unroll
          for (int n=0;n<2;++n){
            int j = n*16 + l15;
            float invf = __expf(-(float)j * 0.28782313662425575f);
            float sn, cs;
            __sincosf((float)lr * invf, &sn, &cs);
            float a = acc[m][n][r2], b2 = acc[m][n+2][r2];
            dst[(long long)lr*1024 + h*64 + j]      = f2bf(a*cs - b2*sn);
            dst[(long long)lr*1024 + h*64 + j + 32] = f2bf(b2*cs + a*sn);
          }
        } else {
          int vcol = (bx-32)*64;
          #pragma unroll
          for (int n=0;n<4;++n)
            Cb[(long long)lr*1024 + vcol + n*16 + l15] = f2bf(acc[m][n][r2]);
        }
      }
    }
    return;
  }

  #pragma unroll
  for (int m=0;m<MF;++m){
    #pragma unroll
    for (int r2=0;r2<4;++r2){
      int lr = by*128 + wr*(MF*16) + m*16 + 4*l4 + r2;
      if (lr >= Me) continue;
      #pragma unroll
      for (int n=0;n<4;++n){
        int col = bx*BN + wc*64 + n*16 + l15;
        float v = acc[m][n][r2];
        if constexpr (EPI == 1){
          if (ks == 0) v += resid[(long long)lr*ldc + col];
          Cf[ks*ksoff + (long long)lr*ldc + col] = v;
        } else if constexpr (EPI == 2){
          float g = 0.5f * v * (1.0f + erff(v * 0.70710678118654752f));
          Cb[(long long)(rbase+lr)*ldc + col] = f2bf(g);
        } else if constexpr (EPI == 3){
          int gi = rbase + lr;
          int ts = tok_list[gi];
          Cf[ks*ksoff + (long long)ts*ldc + col] = v * wgt[gi];
        } else if constexpr (EPI == 5){
          int gi = rbase + lr;
          int ts = tok_list[gi];
          Cb[ks*ksoff + (long long)ts*ldc + col] = f2bf(v * wgt[gi]);
        } else {
          Cb[(long long)lr*ldc + col] = f2bf(v);
        }
      }
    }
  }
}

// ---------------- causal flash attention (V^T in vt[h][d][t]) ----------------
__global__ __launch_bounds__(256) void attn_kernel(
    const unsigned short* __restrict__ Q,
    const unsigned short* __restrict__ K,
    const unsigned short* __restrict__ Vt,
    unsigned short* __restrict__ O)
{
  const int bx = gridDim.x - 1 - blockIdx.x;
  const int h = blockIdx.y;
  const int q0 = bx*64;
  const int tid = threadIdx.x, lane = tid&63, w = tid>>6;
  const int l15 = lane & 15, l4 = lane >> 4;

  __shared__ __align__(16) unsigned short Ks[64*64];
  __shared__ __align__(16) unsigned short Vs[64*64];
  __shared__ __align__(16) unsigned short Ps[4*16*64];
  unsigned short* Pw = Ps + w*1024;

  const int qrow = q0 + w*16 + l15;
  bf16x8 aq[2];
  #pragma unroll
  for (int kk=0;kk<2;++kk)
    aq[kk] = *(const bf16x8*)&Q[(long long)qrow*1024 + h*64 + 32*kk + 8*l4];

  f32x4 o[4] = {};
  float Mx[4] = {-INFINITY,-INFINITY,-INFINITY,-INFINITY};
  float Ls[4] = {0.f,0.f,0.f,0.f};

  const int row_g = q0 + w*16 + 4*l4;
  const int nt = bx + 1;
  for (int it = 0; it < nt; ++it){
    int k0 = it*64;
    #pragma unroll
    for (int i=0;i<2;++i){
      int seg = 4*i + w;
      int row = seg*8 + (lane>>3);
      int cs = (lane&7) ^ (row&7);
      gload16(&K[(long long)(k0+row)*1024 + h*64 + cs*8], &Ks[seg*512]);
      gload16(&Vt[(long long)(h*64+row)*2048 + k0 + cs*8], &Vs[seg*512]);
    }
    __syncthreads();
    f32x4 st[4];
    #pragma unroll
    for (int kt=0;kt<4;++kt){
      f32x4 s = {0.f,0.f,0.f,0.f};
      #pragma unroll
      for (int kk=0;kk<2;++kk){
        int R = kt*16 + l15;
        int ch = (l4+4*kk) ^ (R&7);
        bf16x8 bk = *(const bf16x8*)&Ks[R*64 + ch*8];
        s = __builtin_amdgcn_mfma_f32_16x16x32_bf16(aq[kk], bk, s, 0,0,0);
      }
      st[kt] = s;
    }
    #pragma unroll
    for (int kt=0;kt<4;++kt){
      int col = k0 + kt*16 + l15;
      #pragma unroll
      for (int r=0;r<4;++r){
        float vv = st[kt][r]*0.125f;
        st[kt][r] = (col <= row_g + r) ? vv : -INFINITY;
      }
    }
    float sf[4];
    #pragma unroll
    for (int r=0;r<4;++r){
      float mx = fmaxf(fmaxf(st[0][r],st[1][r]),fmaxf(st[2][r],st[3][r]));
      mx = fmaxf(mx, __shfl_xor(mx,1));
      mx = fmaxf(mx, __shfl_xor(mx,2));
      mx = fmaxf(mx, __shfl_xor(mx,4));
      mx = fmaxf(mx, __shfl_xor(mx,8));
      float mn = fmaxf(Mx[r], mx);
      float sc = __expf(Mx[r]-mn);
      Mx[r]=mn; sf[r]=sc;
      float ls=0.f;
      #pragma unroll
      for (int kt=0;kt<4;++kt){ float pp = __expf(st[kt][r]-mn); st[kt][r]=pp; ls+=pp; }
      Ls[r] = Ls[r]*sc + ls;
    }
    #pragma unroll
    for (int dt=0;dt<4;++dt)
      #pragma unroll
      for (int r=0;r<4;++r) o[dt][r] *= sf[r];
    #pragma unroll
    for (int kt=0;kt<4;++kt)
      #pragma unroll
      for (int r=0;r<4;++r){
        int prow = 4*l4+r, pcol = kt*16+l15;
        int byteoff = (prow*128 + pcol*2) ^ ((prow&7)<<4);
        *(unsigned short*)((char*)Pw + byteoff) = f2bf(st[kt][r]);
      }
    bf16x8 pa[2];
    #pragma unroll
    for (int kk=0;kk<2;++kk){
      int pr = l15;
      int ch = (l4+4*kk) ^ (pr&7);
      pa[kk] = *(const bf16x8*)&Pw[pr*64 + ch*8];
    }
    #pragma unroll
    for (int dt=0;dt<4;++dt){
      #pragma unroll
      for (int kk=0;kk<2;++kk){
        int R = dt*16 + l15;
        int c = (l4 + 4*kk) ^ (R&7);
        bf16x8 bv = *(const bf16x8*)&Vs[R*64 + c*8];
        o[dt] = __builtin_amdgcn_mfma_f32_16x16x32_bf16(pa[kk], bv, o[dt], 0,0,0);
      }
    }
    __syncthreads();
  }
  #pragma unroll
  for (int r=0;r<4;++r){
    float l = Ls[r];
    l += __shfl_xor(l,1); l += __shfl_xor(l,2); l += __shfl_xor(l,4); l += __shfl_xor(l,8);
    Ls[r] = 1.0f / l;
  }
  #pragma unroll
  for (int dt=0;dt<4;++dt)
    #pragma unroll
    for (int r=0;r<4;++r){
      float vv = o[dt][r]*Ls[r];
      int rg = row_g + r;
      O[(long long)rg*1024 + h*64 + dt*16 + l15] = f2bf(vv);
    }
}

__global__ void init_kernel(int* counts, int* cursor){
  int i = threadIdx.x;
  if (i<8){ counts[i]=0; cursor[i]=0; }
}

__global__ void prefix_kernel(const int* counts, int* offs){
  if (threadIdx.x==0){
    int a=0;
    for (int e2=0;e2<8;++e2){ offs[e2]=a; a+=counts[e2]; }
  }
}

__global__ void scatter_kernel(const int* __restrict__ tope, const float* __restrict__ topw,
    const int* __restrict__ offs, int* __restrict__ cursor, int* __restrict__ tok_list, float* __restrict__ wgt){
  int t = blockIdx.x*blockDim.x + threadIdx.x;
  if (t >= 2048) return;
  #pragma unroll
  for (int s=0;s<2;++s){
    int e2 = tope[t*2+s];
    int pos = atomicAdd(&cursor[e2], 1);
    int i = offs[e2] + pos;
    tok_list[i] = t*2+s;
    wgt[i] = topw[t*2+s];
  }
}

// ---------------- final: x1 + bf16 slot partials; block 0 also computes aux ----------------
__global__ __launch_bounds__(256) void final_kernel(const float* __restrict__ x1,
    const unsigned short* __restrict__ slots, int ksn, long long kstride,
    const float* __restrict__ probs, float* __restrict__ out){
  int t = blockIdx.x, tid = threadIdx.x;
  long long b = (long long)t*1024 + tid*4;
  float4 a = *(const float4*)(x1 + b);
  long long s = (long long)t*2048 + tid*4;
  for (int ks=0; ks<ksn; ++ks){
    us4 s0 = *(const us4*)(slots + ks*kstride + s);
    us4 s1 = *(const us4*)(slots + ks*kstride + s + 1024);
    a.x += bf2f(s0[0]) + bf2f(s1[0]);
    a.y += bf2f(s0[1]) + bf2f(s1[1]);
    a.z += bf2f(s0[2]) + bf2f(s1[2]);
    a.w += bf2f(s0[3]) + bf2f(s1[3]);
  }
  *(float4*)(out + b) = a;
  if (blockIdx.x == 0){
    float pe[8] = {0,0,0,0,0,0,0,0};
    for (int tt = tid; tt < 2048; tt += 256){
      #pragma unroll
      for (int e2=0;e2<8;++e2) pe[e2] += probs[tt*8+e2];
    }
    __shared__ float lds[32];
    #pragma unroll
    for (int e2=0;e2<8;++e2){
      float v = pe[e2];
      for (int m=32;m;m>>=1) v += __shfl_xor(v,m);
      if ((tid&63)==0) lds[(tid>>6)*8 + e2] = v;
    }
    __syncthreads();
    if (tid==0){
      float aux = 0.f;
      #pragma unroll
      for (int e2=0;e2<8;++e2){
        float mean = (lds[e2]+lds[8+e2]+lds[16+e2]+lds[24+e2]) * (1.0f/2048.0f);
        aux += mean*mean;
      }
      out[2097152] = 8.0f * aux;
    }
  }
}

extern "C" void kernel_launch(void* const* d_in, const int* in_sizes, int n_in,
                              void* d_out, int out_size, void* d_ws, size_t ws_size,
                              hipStream_t stream)
{
  (void)in_sizes; (void)n_in; (void)out_size; (void)ws_size;
  const float* x    = (const float*)d_in[0];
  const float* qkvw = (const float*)d_in[1];
  const float* outw = (const float*)d_in[2];
  const float* rw   = (const float*)d_in[3];
  const float* w1   = (const float*)d_in[4];
  const float* w2   = (const float*)d_in[5];
  const float* n1w  = (const float*)d_in[6];
  const float* n2w  = (const float*)d_in[7];
  float* out = (float*)d_out;

  char* base = (char*)d_ws;
  const size_t MB = 1ull<<20;
  const int KSO = 4;   // out-proj split-K
  const int KSW = 2;   // w2 split-K

  unsigned short* h_b  = (unsigned short*)(base + 0*MB);
  unsigned short* qb   = (unsigned short*)(base + 4*MB);
  unsigned short* kb   = (unsigned short*)(base + 8*MB);
  unsigned short* ob   = (unsigned short*)(base + 12*MB);
  unsigned short* vb   = (unsigned short*)(base + 16*MB);   // 4MB
  unsigned short* vt   = (unsigned short*)(base + 28*MB);   // 4MB
  unsigned short* hid  = (unsigned short*)(base + 0*MB);    // 32MB alias (after attn phase)

  unsigned short* wbq = (unsigned short*)(base + 32*MB);    // 6MB
  unsigned short* wbo = (unsigned short*)(base + 40*MB);    // 2MB
  unsigned short* wb  = (unsigned short*)(base + 32*MB);    // 64MB (w1 then w2)

  float* x1p   = (float*)(base + 96*MB);                    // KSO x 8MB -> [96,128)
  unsigned short* slots_b = (unsigned short*)(base + 96*MB);// KSW x 8MB bf16 (aliases x1p after rms2)
  float* x1    = (float*)(base + 136*MB);                   // 8MB
  unsigned short* h2b = (unsigned short*)(base + 144*MB);   // 4MB
  char* small_ = base + 148*MB;

  float* probs = (float*)(small_);
  int*   tope  = (int*)(small_ + 256*1024);
  float* topw  = (float*)(small_ + 512*1024);
  int*   tok_list = (int*)(small_ + 768*1024);
  float* wgt   = (float*)(small_ + 1024*1024);
  int*   counts= (int*)(small_ + 1536*1024);
  int*   offs  = (int*)(small_ + 1536*1024 + 256);
  int*   cursor= (int*)(small_ + 1536*1024 + 512);

  init_kernel<<<1,64,0,stream>>>(counts, cursor);
  rmsnorm_kernel<<<2048,256,0,stream>>>(x, n1w, h_b);
  conv_kernel<<<1536,256,0,stream>>>(qkvw, wbq, 3*1024*1024/8);
  conv_kernel<<<512,256,0,stream>>>(outw, wbo, 1024*1024/8);
  // qkv + fused RoPE: M=2048 N=3072 K=1024, BN=64 -> grid (48,16); q->qb, k->kb, v->vb
  gemm_bb<6,false,64><<<dim3(48,16,1),256,0,stream>>>(h_b,1024, wbq,0,1024, 2048,3072,1024, 1,0,
      nullptr,nullptr,nullptr,nullptr,nullptr, nullptr,vb,3072, qb,kb);
  vtrans_kernel<<<dim3(32,16),256,0,stream>>>(vb, vt);
  attn_kernel<<<dim3(32,16),256,0,stream>>>(qb, kb, vt, ob);
  // out-proj: M=2048 N=1024 K=1024, BN=64, KSO=4, fp32 partials -> grid (16,16,4)
  gemm_bb<1,false,64><<<dim3(16,16,KSO),256,0,stream>>>(ob,1024, wbo,0,1024, 2048,1024,1024, KSO,(long long)2048*1024,
      nullptr,nullptr,nullptr,nullptr, x, x1p,nullptr,1024, nullptr,nullptr);
  rmsnorm2_kernel<<<2048,256,0,stream>>>(x1p, KSO, (long long)2048*1024, n2w, rw, x1, h2b,
      probs, tope, topw, counts);
  prefix_kernel<<<1,64,0,stream>>>(counts, offs);
  scatter_kernel<<<8,256,0,stream>>>(tope, topw, offs, cursor, tok_list, wgt);
  // w1: per-expert M<=2048 N=4096 K=1024, BN=128 -> grid (32,16,8)
  conv_kernel<<<16384,256,0,stream>>>(w1, wb, 32*1024*1024/8);
  gemm_bb<2,true,128><<<dim3(32,16,8),256,0,stream>>>(h2b,1024, wb,(long long)4096*1024,1024, 2048,4096,1024, 1,0,
      counts,offs,tok_list,nullptr,nullptr, nullptr,hid,4096, nullptr,nullptr);
  // w2: per-expert M<=2048 N=1024 K=4096, BN=128, KSW=2, bf16 scatter -> grid (8,16,16)
  conv_kernel<<<16384,256,0,stream>>>(w2, wb, 32*1024*1024/8);
  gemm_bb<5,false,128><<<dim3(8,16,8*KSW),256,0,stream>>>(hid,4096, wb,(long long)4096*1024,4096, 2048,1024,4096, KSW,(long long)4096*1024,
      counts,offs,tok_list,wgt,nullptr, nullptr,slots_b,1024, nullptr,nullptr);
  final_kernel<<<2048,256,0,stream>>>(x1, slots_b, KSW, (long long)4096*1024, probs, out);
}

// Round 19
// 374.357 us; speedup vs baseline: 1.0549x; 1.0549x over previous
//
#include <hip/hip_runtime.h>
#include <cstdint>
#include <math.h>

typedef float f32x4 __attribute__((ext_vector_type(4)));
typedef __bf16 bf16x8 __attribute__((ext_vector_type(8)));
typedef unsigned short us4 __attribute__((ext_vector_type(4)));
typedef unsigned short us8 __attribute__((ext_vector_type(8)));

#define DEV static __device__ __forceinline__

DEV unsigned short f2bf(float f){
  union { __bf16 h; unsigned short u; } cv; cv.h = (__bf16)f; return cv.u;
}
DEV float bf2f(unsigned short u){ return __uint_as_float((unsigned int)u << 16); }

DEV void gload16(const void* g, void* l){
  __builtin_amdgcn_global_load_lds((__attribute__((address_space(1))) void*)g,
                                   (__attribute__((address_space(3))) void*)l, 16, 0, 0);
}

// ---------------- fp32 -> bf16 weight conversion (two sources, one launch) ----------------
__global__ __launch_bounds__(256) void conv2_kernel(const float* __restrict__ srcA, unsigned short* __restrict__ dstA, int nA8,
    const float* __restrict__ srcB, unsigned short* __restrict__ dstB, int nB8){
  int blk = blockIdx.x;
  const float* src; unsigned short* dst; int i;
  int nblkA = (nA8 + 255) >> 8;
  if (blk < nblkA){ src = srcA; dst = dstA; i = blk*256 + threadIdx.x; if (i >= nA8) return; }
  else            { src = srcB; dst = dstB; i = (blk-nblkA)*256 + threadIdx.x; if (i >= nB8) return; }
  float4 a = ((const float4*)src)[2*i];
  float4 b = ((const float4*)src)[2*i+1];
  us8 o = { f2bf(a.x), f2bf(a.y), f2bf(a.z), f2bf(a.w),
            f2bf(b.x), f2bf(b.y), f2bf(b.z), f2bf(b.w) };
  ((us8*)dst)[i] = o;
}

__global__ __launch_bounds__(256) void conv_kernel(const float* __restrict__ src,
    unsigned short* __restrict__ dst, int n8){
  int i = blockIdx.x*256 + threadIdx.x;
  if (i >= n8) return;
  float4 a = ((const float4*)src)[2*i];
  float4 b = ((const float4*)src)[2*i+1];
  us8 o = { f2bf(a.x), f2bf(a.y), f2bf(a.z), f2bf(a.w),
            f2bf(b.x), f2bf(b.y), f2bf(b.z), f2bf(b.w) };
  ((us8*)dst)[i] = o;
}

// ---------------- V transpose: vb[t][h*64+d] -> vt[h][d][t] ----------------
__global__ __launch_bounds__(256) void vtrans_kernel(const unsigned short* __restrict__ vb,
    unsigned short* __restrict__ vt){
  int tt = blockIdx.x, h = blockIdx.y;
  int t0 = tt*64;
  __shared__ unsigned short tile[64][72];
  int r = threadIdx.x >> 2, cb = (threadIdx.x & 3) * 16;
  const unsigned short* src = vb + (long long)(t0+r)*1024 + h*64 + cb;
  us8 a = *(const us8*)src;
  us8 b = *(const us8*)(src+8);
  #pragma unroll
  for (int i=0;i<8;++i){ tile[r][cb+i] = a[i]; tile[r][cb+8+i] = b[i]; }
  __syncthreads();
  unsigned short o[16];
  #pragma unroll
  for (int i=0;i<16;++i) o[i] = tile[cb+i][r];
  unsigned short* dst = vt + (long long)(h*64+r)*2048 + t0 + cb;
  *(us8*)dst = *(us8*)&o[0];
  *(us8*)(dst+8) = *(us8*)&o[8];
}

// ---------------- RMSNorm 1 (block 0 also clears MoE counts) ----------------
__global__ __launch_bounds__(256) void rmsnorm_kernel(const float* __restrict__ x, const float* __restrict__ w,
    unsigned short* __restrict__ ob, int* __restrict__ counts){
  int t = blockIdx.x, tid = threadIdx.x;
  if (t == 0 && tid < 8) counts[tid] = 0;
  float4 xv = *(const float4*)(x + (long long)t*1024 + tid*4);
  float ss = xv.x*xv.x + xv.y*xv.y + xv.z*xv.z + xv.w*xv.w;
  for (int m=32;m;m>>=1) ss += __shfl_xor(ss,m);
  __shared__ float lds[4];
  if ((tid&63)==0) lds[tid>>6] = ss;
  __syncthreads();
  float tot = lds[0]+lds[1]+lds[2]+lds[3];
  float inv = rsqrtf(tot*(1.0f/1024.0f) + 1.1920928955078125e-07f);
  float4 wv = *(const float4*)(w + tid*4);
  us4 rb = { f2bf(xv.x*inv*wv.x), f2bf(xv.y*inv*wv.y), f2bf(xv.z*inv*wv.z), f2bf(xv.w*inv*wv.w) };
  *(us4*)&ob[(long long)t*1024 + tid*4] = rb;
}

// ---------------- RMSNorm 2 + fused router/top2 ----------------
__global__ __launch_bounds__(256) void rmsnorm2_kernel(const float* __restrict__ xp, int ksn, long long kstride,
    const float* __restrict__ w, const float* __restrict__ rw,
    float* __restrict__ x1, unsigned short* __restrict__ hb,
    float* __restrict__ probs, int* __restrict__ tope, float* __restrict__ topw, int* __restrict__ counts){
  int t = blockIdx.x, tid = threadIdx.x;
  long long b = (long long)t*1024 + tid*4;
  float4 xv = {0.f,0.f,0.f,0.f};
  for (int ks=0; ks<ksn; ++ks){
    float4 a = *(const float4*)(xp + ks*kstride + b);
    xv.x+=a.x; xv.y+=a.y; xv.z+=a.z; xv.w+=a.w;
  }
  *(float4*)(x1 + b) = xv;
  float ss = xv.x*xv.x + xv.y*xv.y + xv.z*xv.z + xv.w*xv.w;
  for (int m=32;m;m>>=1) ss += __shfl_xor(ss,m);
  __shared__ float lds[32];
  if ((tid&63)==0) lds[tid>>6] = ss;
  __syncthreads();
  float tot = lds[0]+lds[1]+lds[2]+lds[3];
  float inv = rsqrtf(tot*(1.0f/1024.0f) + 1.1920928955078125e-07f);
  float4 wv = *(const float4*)(w + tid*4);
  float r0 = xv.x*inv*wv.x, r1 = xv.y*inv*wv.y, r2 = xv.z*inv*wv.z, r3 = xv.w*inv*wv.w;
  us4 rb = { f2bf(r0), f2bf(r1), f2bf(r2), f2bf(r3) };
  *(us4*)&hb[b] = rb;
  float pe[8];
  #pragma unroll
  for (int e2=0;e2<8;++e2){
    float4 rv = *(const float4*)(rw + e2*1024 + tid*4);
    pe[e2] = r0*rv.x + r1*rv.y + r2*rv.z + r3*rv.w;
  }
  __syncthreads();
  #pragma unroll
  for (int e2=0;e2<8;++e2){
    float v = pe[e2];
    for (int m=32;m;m>>=1) v += __shfl_xor(v,m);
    if ((tid&63)==0) lds[(tid>>6)*8+e2] = v;
  }
  __syncthreads();
  if (tid==0){
    float lg[8], pp[8];
    #pragma unroll
    for (int e2=0;e2<8;++e2) lg[e2] = lds[e2]+lds[8+e2]+lds[16+e2]+lds[24+e2];
    float mx = lg[0];
    for (int e2=1;e2<8;++e2) mx = fmaxf(mx, lg[e2]);
    float s = 0.f;
    for (int e2=0;e2<8;++e2){ pp[e2] = __expf(lg[e2]-mx); s += pp[e2]; }
    float invs = 1.0f/s;
    int i0 = 0;
    for (int e2=1;e2<8;++e2) if (pp[e2] > pp[i0]) i0 = e2;
    int i1 = (i0==0)?1:0;
    for (int e2=0;e2<8;++e2) if (e2!=i0 && pp[e2] > pp[i1]) i1 = e2;
    for (int e2=0;e2<8;++e2) probs[t*8+e2] = pp[e2]*invs;
    float p0 = pp[i0], p1 = pp[i1], wsum = p0+p1;
    tope[t*2] = i0; tope[t*2+1] = i1;
    topw[t*2] = p0/wsum; topw[t*2+1] = p1/wsum;
    atomicAdd(&counts[i0],1); atomicAdd(&counts[i1],1);
  }
}

// ---------------- m97-replica GEMM  C[M,N] = A[M,K](bf16) * B[N,K]^T(bf16) ----------------
// BM=128, BN in {128,64}. 256 thr, 4 waves. BK=64, single-buffered LDS,
// global_load_lds both operands, pre-swizzled source c^(R&7); 2-barrier loop (m97/m114).
// EPI: 1 = fp32 (+resid if ks==0), 2 = gelu->bf16 rows rbase+lr,
//      4 = plain bf16, 5 = *wgt scatter bf16, 6 = fused-RoPE qkv (q->Q2, k->K2, v->Cb)
template<int EPI, bool GATHER, int BN>
__global__ __launch_bounds__(256) void gemm_bb(
    const unsigned short* __restrict__ A, int lda,
    const unsigned short* __restrict__ Bb, long long bstride, int ldb,
    int M, int N, int K, int KS, long long ksoff,
    const int* __restrict__ counts, const int* __restrict__ offs,
    const int* __restrict__ tok_list, const float* __restrict__ wgt,
    const float* __restrict__ resid,
    float* __restrict__ Cf, unsigned short* __restrict__ Cb, int ldc,
    unsigned short* __restrict__ Q2, unsigned short* __restrict__ K2)
{
  constexpr int MF = (BN==128) ? 4 : 2;       // m-frags per wave
  constexpr int BLOADS = BN/32;               // B gload16 per thread
  const int z = blockIdx.z;
  const int e = z / KS, ks = z - e*KS;
  const int Me = counts ? counts[e] : M;
  const int by = blockIdx.y;
  if (by * 128 >= Me) return;
  const int rbase = offs ? offs[e] : 0;
  const int bx = blockIdx.x;
  const unsigned short* B = Bb + (long long)e * bstride;
  const int kn = K / KS;
  const int kbeg = ks * kn;

  __shared__ __align__(16) unsigned short As[128*64];
  __shared__ __align__(16) unsigned short Bs[BN*64];

  const int tid = threadIdx.x, lane = tid & 63, w = tid >> 6;
  const int wr = (BN==128) ? (w >> 1) : w;
  const int wc = (BN==128) ? (w & 1) : 0;
  const int l15 = lane & 15, l4 = lane >> 4;

  const unsigned short* asrc[4];
  #pragma unroll
  for (int j=0;j<4;++j){
    int G = j*256 + tid;
    int R = G >> 3, c = G & 7;
    int sc = c ^ (R & 7);
    int lr = by*128 + R; if (lr >= Me) lr = Me-1;
    int li = rbase + lr;
    int ar = GATHER ? (tok_list[li] >> 1) : li;
    asrc[j] = A + (long long)ar*lda + kbeg + sc*8;
  }
  const unsigned short* bsrc[BLOADS];
  #pragma unroll
  for (int j=0;j<BLOADS;++j){
    int G = j*256 + tid;
    int R = G >> 3, c = G & 7;
    int sc = c ^ (R & 7);
    bsrc[j] = B + (long long)(bx*BN + R)*ldb + kbeg + sc*8;
  }

  f32x4 acc[MF][4] = {};

  for (int k0 = 0; k0 < kn; k0 += 64){
    __syncthreads();
    #pragma unroll
    for (int j=0;j<4;++j) gload16(asrc[j] + k0, &As[(j*256+tid)*8]);
    #pragma unroll
    for (int j=0;j<BLOADS;++j) gload16(bsrc[j] + k0, &Bs[(j*256+tid)*8]);
    __syncthreads();
    #pragma unroll
    for (int kk=0;kk<2;++kk){
      bf16x8 af[MF], bfr[4];
      #pragma unroll
      for (int m=0;m<MF;++m){
        int R = wr*(MF*16) + m*16 + l15;
        int c = (l4 + 4*kk) ^ (R&7);
        af[m] = *(const bf16x8*)&As[R*64 + c*8];
      }
      #pragma unroll
      for (int n=0;n<4;++n){
        int R = wc*64 + n*16 + l15;
        int c = (l4 + 4*kk) ^ (R&7);
        bfr[n] = *(const bf16x8*)&Bs[R*64 + c*8];
      }
      #pragma unroll
      for (int m=0;m<MF;++m)
        #pragma unroll
        for (int n=0;n<4;++n)
          acc[m][n] = __builtin_amdgcn_mfma_f32_16x16x32_bf16(af[m], bfr[n], acc[m][n], 0, 0, 0);
    }
  }

  if constexpr (EPI == 6){
    // qkv with fused RoPE. N=3072: bx 0-15 = q heads, 16-31 = k heads, 32-47 = v.
    #pragma unroll
    for (int m=0;m<MF;++m){
      #pragma unroll
      for (int r2=0;r2<4;++r2){
        int lr = by*128 + wr*(MF*16) + m*16 + 4*l4 + r2;
        if (bx < 32){
          unsigned short* dst = (bx < 16) ? Q2 : K2;
          int h = bx & 15;
          #pragma unroll
          for (int n=0;n<2;++n){
            int j = n*16 + l15;
            float invf = __expf(-(float)j * 0.28782313662425575f);
            float sn, cs;
            __sincosf((float)lr * invf, &sn, &cs);
            float a = acc[m][n][r2], b2 = acc[m][n+2][r2];
            dst[(long long)lr*1024 + h*64 + j]      = f2bf(a*cs - b2*sn);
            dst[(long long)lr*1024 + h*64 + j + 32] = f2bf(b2*cs + a*sn);
          }
        } else {
          int vcol = (bx-32)*64;
          #pragma unroll
          for (int n=0;n<4;++n)
            Cb[(long long)lr*1024 + vcol + n*16 + l15] = f2bf(acc[m][n][r2]);
        }
      }
    }
    return;
  }

  #pragma unroll
  for (int m=0;m<MF;++m){
    #pragma unroll
    for (int r2=0;r2<4;++r2){
      int lr = by*128 + wr*(MF*16) + m*16 + 4*l4 + r2;
      if (lr >= Me) continue;
      #pragma unroll
      for (int n=0;n<4;++n){
        int col = bx*BN + wc*64 + n*16 + l15;
        float v = acc[m][n][r2];
        if constexpr (EPI == 1){
          if (ks == 0) v += resid[(long long)lr*ldc + col];
          Cf[ks*ksoff + (long long)lr*ldc + col] = v;
        } else if constexpr (EPI == 2){
          float g = 0.5f * v * (1.0f + erff(v * 0.70710678118654752f));
          Cb[(long long)(rbase+lr)*ldc + col] = f2bf(g);
        } else if constexpr (EPI == 5){
          int gi = rbase + lr;
          int ts = tok_list[gi];
          Cb[ks*ksoff + (long long)ts*ldc + col] = f2bf(v * wgt[gi]);
        } else {
          Cb[(long long)lr*ldc + col] = f2bf(v);
        }
      }
    }
  }
}

// ---------------- causal flash attention (V^T in vt[h][d][t]) ----------------
__global__ __launch_bounds__(256) void attn_kernel(
    const unsigned short* __restrict__ Q,
    const unsigned short* __restrict__ K,
    const unsigned short* __restrict__ Vt,
    unsigned short* __restrict__ O)
{
  const int bx = gridDim.x - 1 - blockIdx.x;
  const int h = blockIdx.y;
  const int q0 = bx*64;
  const int tid = threadIdx.x, lane = tid&63, w = tid>>6;
  const int l15 = lane & 15, l4 = lane >> 4;

  __shared__ __align__(16) unsigned short Ks[64*64];
  __shared__ __align__(16) unsigned short Vs[64*64];
  __shared__ __align__(16) unsigned short Ps[4*16*64];
  unsigned short* Pw = Ps + w*1024;

  const int qrow = q0 + w*16 + l15;
  bf16x8 aq[2];
  #pragma unroll
  for (int kk=0;kk<2;++kk)
    aq[kk] = *(const bf16x8*)&Q[(long long)qrow*1024 + h*64 + 32*kk + 8*l4];

  f32x4 o[4] = {};
  float Mx[4] = {-INFINITY,-INFINITY,-INFINITY,-INFINITY};
  float Ls[4] = {0.f,0.f,0.f,0.f};

  const int row_g = q0 + w*16 + 4*l4;
  const int nt = bx + 1;
  for (int it = 0; it < nt; ++it){
    int k0 = it*64;
    #pragma unroll
    for (int i=0;i<2;++i){
      int seg = 4*i + w;
      int row = seg*8 + (lane>>3);
      int cs = (lane&7) ^ (row&7);
      gload16(&K[(long long)(k0+row)*1024 + h*64 + cs*8], &Ks[seg*512]);
      gload16(&Vt[(long long)(h*64+row)*2048 + k0 + cs*8], &Vs[seg*512]);
    }
    __syncthreads();
    f32x4 st[4];
    #pragma unroll
    for (int kt=0;kt<4;++kt){
      f32x4 s = {0.f,0.f,0.f,0.f};
      #pragma unroll
      for (int kk=0;kk<2;++kk){
        int R = kt*16 + l15;
        int ch = (l4+4*kk) ^ (R&7);
        bf16x8 bk = *(const bf16x8*)&Ks[R*64 + ch*8];
        s = __builtin_amdgcn_mfma_f32_16x16x32_bf16(aq[kk], bk, s, 0,0,0);
      }
      st[kt] = s;
    }
    #pragma unroll
    for (int kt=0;kt<4;++kt){
      int col = k0 + kt*16 + l15;
      #pragma unroll
      for (int r=0;r<4;++r){
        float vv = st[kt][r]*0.125f;
        st[kt][r] = (col <= row_g + r) ? vv : -INFINITY;
      }
    }
    float sf[4];
    #pragma unroll
    for (int r=0;r<4;++r){
      float mx = fmaxf(fmaxf(st[0][r],st[1][r]),fmaxf(st[2][r],st[3][r]));
      mx = fmaxf(mx, __shfl_xor(mx,1));
      mx = fmaxf(mx, __shfl_xor(mx,2));
      mx = fmaxf(mx, __shfl_xor(mx,4));
      mx = fmaxf(mx, __shfl_xor(mx,8));
      float mn = fmaxf(Mx[r], mx);
      float sc = __expf(Mx[r]-mn);
      Mx[r]=mn; sf[r]=sc;
      float ls=0.f;
      #pragma unroll
      for (int kt=0;kt<4;++kt){ float pp = __expf(st[kt][r]-mn); st[kt][r]=pp; ls+=pp; }
      Ls[r] = Ls[r]*sc + ls;
    }
    #pragma unroll
    for (int dt=0;dt<4;++dt)
      #pragma unroll
      for (int r=0;r<4;++r) o[dt][r] *= sf[r];
    #pragma unroll
    for (int kt=0;kt<4;++kt)
      #pragma unroll
      for (int r=0;r<4;++r){
        int prow = 4*l4+r, pcol = kt*16+l15;
        int byteoff = (prow*128 + pcol*2) ^ ((prow&7)<<4);
        *(unsigned short*)((char*)Pw + byteoff) = f2bf(st[kt][r]);
      }
    bf16x8 pa[2];
    #pragma unroll
    for (int kk=0;kk<2;++kk){
      int pr = l15;
      int ch = (l4+4*kk) ^ (pr&7);
      pa[kk] = *(const bf16x8*)&Pw[pr*64 + ch*8];
    }
    #pragma unroll
    for (int dt=0;dt<4;++dt){
      #pragma unroll
      for (int kk=0;kk<2;++kk){
        int R = dt*16 + l15;
        int c = (l4 + 4*kk) ^ (R&7);
        bf16x8 bv = *(const bf16x8*)&Vs[R*64 + c*8];
        o[dt] = __builtin_amdgcn_mfma_f32_16x16x32_bf16(pa[kk], bv, o[dt], 0,0,0);
      }
    }
    __syncthreads();
  }
  #pragma unroll
  for (int r=0;r<4;++r){
    float l = Ls[r];
    l += __shfl_xor(l,1); l += __shfl_xor(l,2); l += __shfl_xor(l,4); l += __shfl_xor(l,8);
    Ls[r] = 1.0f / l;
  }
  #pragma unroll
  for (int dt=0;dt<4;++dt)
    #pragma unroll
    for (int r=0;r<4;++r){
      float vv = o[dt][r]*Ls[r];
      int rg = row_g + r;
      O[(long long)rg*1024 + h*64 + dt*16 + l15] = f2bf(vv);
    }
}

// ---------------- fused prefix + scatter (single block) ----------------
__global__ __launch_bounds__(1024) void scatter2_kernel(const int* __restrict__ tope, const float* __restrict__ topw,
    const int* __restrict__ counts, int* __restrict__ offs,
    int* __restrict__ tok_list, float* __restrict__ wgt){
  __shared__ int soffs[8];
  __shared__ int scur[8];
  int tid = threadIdx.x;
  if (tid == 0){
    int a = 0;
    for (int e2=0;e2<8;++e2){ soffs[e2] = a; offs[e2] = a; a += counts[e2]; }
  }
  if (tid < 8) scur[tid] = 0;
  __syncthreads();
  for (int t = tid; t < 2048; t += 1024){
    #pragma unroll
    for (int s=0;s<2;++s){
      int e2 = tope[t*2+s];
      int pos = atomicAdd(&scur[e2], 1);
      int i = soffs[e2] + pos;
      tok_list[i] = t*2+s;
      wgt[i] = topw[t*2+s];
    }
  }
}

// ---------------- final: x1 + bf16 slot partials; block 0 also computes aux ----------------
__global__ __launch_bounds__(256) void final_kernel(const float* __restrict__ x1,
    const unsigned short* __restrict__ slots, int ksn, long long kstride,
    const float* __restrict__ probs, float* __restrict__ out){
  int t = blockIdx.x, tid = threadIdx.x;
  long long b = (long long)t*1024 + tid*4;
  float4 a = *(const float4*)(x1 + b);
  long long s = (long long)t*2048 + tid*4;
  for (int ks=0; ks<ksn; ++ks){
    us4 s0 = *(const us4*)(slots + ks*kstride + s);
    us4 s1 = *(const us4*)(slots + ks*kstride + s + 1024);
    a.x += bf2f(s0[0]) + bf2f(s1[0]);
    a.y += bf2f(s0[1]) + bf2f(s1[1]);
    a.z += bf2f(s0[2]) + bf2f(s1[2]);
    a.w += bf2f(s0[3]) + bf2f(s1[3]);
  }
  *(float4*)(out + b) = a;
  if (blockIdx.x == 0){
    float pe[8] = {0,0,0,0,0,0,0,0};
    for (int tt = tid; tt < 2048; tt += 256){
      #pragma unroll
      for (int e2=0;e2<8;++e2) pe[e2] += probs[tt*8+e2];
    }
    __shared__ float lds[32];
    #pragma unroll
    for (int e2=0;e2<8;++e2){
      float v = pe[e2];
      for (int m=32;m;m>>=1) v += __shfl_xor(v,m);
      if ((tid&63)==0) lds[(tid>>6)*8 + e2] = v;
    }
    __syncthreads();
    if (tid==0){
      float aux = 0.f;
      #pragma unroll
      for (int e2=0;e2<8;++e2){
        float mean = (lds[e2]+lds[8+e2]+lds[16+e2]+lds[24+e2]) * (1.0f/2048.0f);
        aux += mean*mean;
      }
      out[2097152] = 8.0f * aux;
    }
  }
}

extern "C" void kernel_launch(void* const* d_in, const int* in_sizes, int n_in,
                              void* d_out, int out_size, void* d_ws, size_t ws_size,
                              hipStream_t stream)
{
  (void)in_sizes; (void)n_in; (void)out_size; (void)ws_size;
  const float* x    = (const float*)d_in[0];
  const float* qkvw = (const float*)d_in[1];
  const float* outw = (const float*)d_in[2];
  const float* rw   = (const float*)d_in[3];
  const float* w1   = (const float*)d_in[4];
  const float* w2   = (const float*)d_in[5];
  const float* n1w  = (const float*)d_in[6];
  const float* n2w  = (const float*)d_in[7];
  float* out = (float*)d_out;

  char* base = (char*)d_ws;
  const size_t MB = 1ull<<20;
  const int KSO = 4;   // out-proj split-K
  const int KSW = 2;   // w2 split-K

  unsigned short* h_b  = (unsigned short*)(base + 0*MB);
  unsigned short* qb   = (unsigned short*)(base + 4*MB);
  unsigned short* kb   = (unsigned short*)(base + 8*MB);
  unsigned short* ob   = (unsigned short*)(base + 12*MB);
  unsigned short* vb   = (unsigned short*)(base + 16*MB);   // 4MB
  unsigned short* vt   = (unsigned short*)(base + 28*MB);   // 4MB
  unsigned short* hid  = (unsigned short*)(base + 0*MB);    // 32MB alias (after attn phase)

  unsigned short* wbq = (unsigned short*)(base + 32*MB);    // 6MB
  unsigned short* wbo = (unsigned short*)(base + 40*MB);    // 2MB
  unsigned short* wb  = (unsigned short*)(base + 32*MB);    // 64MB (w1 then w2)

  float* x1p   = (float*)(base + 96*MB);                    // KSO x 8MB -> [96,128)
  unsigned short* slots_b = (unsigned short*)(base + 96*MB);// KSW x 8MB bf16 (aliases x1p after rms2)
  float* x1    = (float*)(base + 136*MB);                   // 8MB
  unsigned short* h2b = (unsigned short*)(base + 144*MB);   // 4MB
  char* small_ = base + 148*MB;

  float* probs = (float*)(small_);
  int*   tope  = (int*)(small_ + 256*1024);
  float* topw  = (float*)(small_ + 512*1024);
  int*   tok_list = (int*)(small_ + 768*1024);
  float* wgt   = (float*)(small_ + 1024*1024);
  int*   counts= (int*)(small_ + 1536*1024);
  int*   offs  = (int*)(small_ + 1536*1024 + 256);

  rmsnorm_kernel<<<2048,256,0,stream>>>(x, n1w, h_b, counts);
  // qkv weights (3M x8) + out-proj weights (1M/8) in one launch
  conv2_kernel<<<1536+512,256,0,stream>>>(qkvw, wbq, 3*1024*1024/8, outw, wbo, 1024*1024/8);
  // qkv + fused RoPE: M=2048 N=3072 K=1024, BN=64 -> grid (48,16); q->qb, k->kb, v->vb
  gemm_bb<6,false,64><<<dim3(48,16,1),256,0,stream>>>(h_b,1024, wbq,0,1024, 2048,3072,1024, 1,0,
      nullptr,nullptr,nullptr,nullptr,nullptr, nullptr,vb,3072, qb,kb);
  vtrans_kernel<<<dim3(32,16),256,0,stream>>>(vb, vt);
  attn_kernel<<<dim3(32,16),256,0,stream>>>(qb, kb, vt, ob);
  // out-proj: M=2048 N=1024 K=1024, BN=64, KSO=4, fp32 partials -> grid (16,16,4)
  gemm_bb<1,false,64><<<dim3(16,16,KSO),256,0,stream>>>(ob,1024, wbo,0,1024, 2048,1024,1024, KSO,(long long)2048*1024,
      nullptr,nullptr,nullptr,nullptr, x, x1p,nullptr,1024, nullptr,nullptr);
  rmsnorm2_kernel<<<2048,256,0,stream>>>(x1p, KSO, (long long)2048*1024, n2w, rw, x1, h2b,
      probs, tope, topw, counts);
  scatter2_kernel<<<1,1024,0,stream>>>(tope, topw, counts, offs, tok_list, wgt);
  // w1: per-expert M<=2048 N=4096 K=1024, BN=128 -> grid (32,16,8)
  conv_kernel<<<16384,256,0,stream>>>(w1, wb, 32*1024*1024/8);
  gemm_bb<2,true,128><<<dim3(32,16,8),256,0,stream>>>(h2b,1024, wb,(long long)4096*1024,1024, 2048,4096,1024, 1,0,
      counts,offs,tok_list,nullptr,nullptr, nullptr,hid,4096, nullptr,nullptr);
  // w2: per-expert M<=2048 N=1024 K=4096, BN=128, KSW=2, bf16 scatter -> grid (8,16,16)
  conv_kernel<<<16384,256,0,stream>>>(w2, wb, 32*1024*1024/8);
  gemm_bb<5,false,128><<<dim3(8,16,8*KSW),256,0,stream>>>(hid,4096, wb,(long long)4096*1024,4096, 2048,1024,4096, KSW,(long long)4096*1024,
      counts,offs,tok_list,wgt,nullptr, nullptr,slots_b,1024, nullptr,nullptr);
  final_kernel<<<2048,256,0,stream>>>(x1, slots_b, KSW, (long long)4096*1024, probs, out);
}